// Round 1
// baseline (326.895 us; speedup 1.0000x reference)
//
#include <hip/hip_runtime.h>

#define HWSZ 65536      // H*W
#define KSEL 32768u     // int(0.5*H*W)
#define CCH  128        // channels
#define BN   4          // batch
#define NG   (CCH * BN) // 512 groups, group g = b*CCH + c (contiguous HWSZ floats each)
#define NT   512        // threads per block

// entropy value + its order-preserving bit pattern (all values > 0; guard -0.0)
__device__ __forceinline__ unsigned ebits(float h, float w, float* eo) {
    float f1 = h * w;
    float e  = -f1 * logf(f1);
    *eo = e;
    unsigned b = __float_as_uint(e);
    return (b == 0x80000000u) ? 0u : b;   // -0.0 -> +0.0 ordering-wise
}

// ---------------- Pass 1: level-1 histogram (bits[30:20]) + total sum ----------------
__global__ void __launch_bounds__(NT) pass1_kernel(
    const float* __restrict__ hsi, const float* __restrict__ wp,
    double* __restrict__ total_sum, unsigned* __restrict__ prefix1,
    unsigned* __restrict__ c1out) {
    __shared__ unsigned hist[4][2048];     // 4 replicas: hot-bin atomic relief
    __shared__ unsigned chunkSum[NT];
    __shared__ double   red[NT / 64];
    const int g   = blockIdx.x;
    const int tid = threadIdx.x;
    const float w = wp[0];
    for (int i = tid; i < 4 * 2048; i += NT) (&hist[0][0])[i] = 0u;
    __syncthreads();

    const float4* __restrict__ src = (const float4*)(hsi + (size_t)g * HWSZ);
    unsigned* myhist = hist[tid >> 7];     // replica per wave-pair
    double lsum = 0.0;
    for (int i = 0; i < HWSZ / 4 / NT; ++i) {   // 32 coalesced float4 iters/thread
        float4 v = src[(size_t)i * NT + tid];
        float e; unsigned b;
        b = ebits(v.x, w, &e); lsum += (double)e; atomicAdd(&myhist[b >> 20], 1u);
        b = ebits(v.y, w, &e); lsum += (double)e; atomicAdd(&myhist[b >> 20], 1u);
        b = ebits(v.z, w, &e); lsum += (double)e; atomicAdd(&myhist[b >> 20], 1u);
        b = ebits(v.w, w, &e); lsum += (double)e; atomicAdd(&myhist[b >> 20], 1u);
    }
    #pragma unroll
    for (int off = 32; off > 0; off >>= 1) lsum += __shfl_down(lsum, off);
    if ((tid & 63) == 0) red[tid >> 6] = lsum;
    __syncthreads();
    for (int b = tid; b < 2048; b += NT)
        hist[0][b] += hist[1][b] + hist[2][b] + hist[3][b];
    __syncthreads();
    chunkSum[tid] = hist[0][tid * 4] + hist[0][tid * 4 + 1] +
                    hist[0][tid * 4 + 2] + hist[0][tid * 4 + 3];
    __syncthreads();
    if (tid == 0) {
        double ts = 0.0;
        for (int i = 0; i < NT / 64; ++i) ts += red[i];
        total_sum[g] = ts;
        unsigned acc = 0;
        int ch = NT - 1;
        for (; ch > 0; --ch) {                // scan chunks from the top
            unsigned s = chunkSum[ch];
            if (acc + s >= KSEL) break;
            acc += s;
        }
        int b = ch * 4 + 3;
        for (; b > ch * 4; --b) {             // bins within chunk, high->low
            unsigned h = hist[0][b];
            if (acc + h >= KSEL) break;
            acc += h;
        }
        prefix1[g] = (unsigned)b;             // bits[30:20] of k-th largest
        c1out[g]   = acc;                     // # strictly above that bin
    }
}

// ---------------- Pass 2: level-2 histogram (bits[19:9]) within candidate bin ----------------
__global__ void __launch_bounds__(NT) pass2_kernel(
    const float* __restrict__ hsi, const float* __restrict__ wp,
    const unsigned* __restrict__ prefix1, const unsigned* __restrict__ c1in,
    unsigned* __restrict__ prefix12, unsigned* __restrict__ c12out) {
    __shared__ unsigned hist[2048];
    __shared__ unsigned chunkSum[NT];
    const int g   = blockIdx.x;
    const int tid = threadIdx.x;
    const float w = wp[0];
    const unsigned p1 = prefix1[g];
    for (int i = tid; i < 2048; i += NT) hist[i] = 0u;
    __syncthreads();

    const float4* __restrict__ src = (const float4*)(hsi + (size_t)g * HWSZ);
    for (int i = 0; i < HWSZ / 4 / NT; ++i) {
        float4 v = src[(size_t)i * NT + tid];
        float e; unsigned b;
        b = ebits(v.x, w, &e); if ((b >> 20) == p1) atomicAdd(&hist[(b >> 9) & 0x7FFu], 1u);
        b = ebits(v.y, w, &e); if ((b >> 20) == p1) atomicAdd(&hist[(b >> 9) & 0x7FFu], 1u);
        b = ebits(v.z, w, &e); if ((b >> 20) == p1) atomicAdd(&hist[(b >> 9) & 0x7FFu], 1u);
        b = ebits(v.w, w, &e); if ((b >> 20) == p1) atomicAdd(&hist[(b >> 9) & 0x7FFu], 1u);
    }
    __syncthreads();
    chunkSum[tid] = hist[tid * 4] + hist[tid * 4 + 1] +
                    hist[tid * 4 + 2] + hist[tid * 4 + 3];
    __syncthreads();
    if (tid == 0) {
        unsigned acc = c1in[g];
        int ch = NT - 1;
        for (; ch > 0; --ch) {
            unsigned s = chunkSum[ch];
            if (acc + s >= KSEL) break;
            acc += s;
        }
        int b = ch * 4 + 3;
        for (; b > ch * 4; --b) {
            unsigned h = hist[b];
            if (acc + h >= KSEL) break;
            acc += h;
        }
        prefix12[g] = (p1 << 11) | (unsigned)b;   // bits[30:9] of k-th largest
        c12out[g]   = acc;
    }
}

// ---------------- Pass 3: level-3 (bits[8:0]) — each bin is one exact float; finalize top-k sum ----------------
__global__ void __launch_bounds__(NT) pass3_kernel(
    const float* __restrict__ hsi, const float* __restrict__ wp,
    const unsigned* __restrict__ prefix12, const unsigned* __restrict__ c12in,
    double* __restrict__ topk_sum) {
    __shared__ unsigned hist[512];
    __shared__ double   red[NT / 64];
    const int g   = blockIdx.x;
    const int tid = threadIdx.x;
    const float w = wp[0];
    const unsigned p12 = prefix12[g];
    for (int i = tid; i < 512; i += NT) hist[i] = 0u;
    __syncthreads();

    const float4* __restrict__ src = (const float4*)(hsi + (size_t)g * HWSZ);
    double sgt = 0.0;    // sum of values strictly above the level-2 bin range
    for (int i = 0; i < HWSZ / 4 / NT; ++i) {
        float4 v = src[(size_t)i * NT + tid];
        float e; unsigned b, p;
        b = ebits(v.x, w, &e); p = b >> 9;
        if (p > p12) sgt += (double)e; else if (p == p12) atomicAdd(&hist[b & 0x1FFu], 1u);
        b = ebits(v.y, w, &e); p = b >> 9;
        if (p > p12) sgt += (double)e; else if (p == p12) atomicAdd(&hist[b & 0x1FFu], 1u);
        b = ebits(v.z, w, &e); p = b >> 9;
        if (p > p12) sgt += (double)e; else if (p == p12) atomicAdd(&hist[b & 0x1FFu], 1u);
        b = ebits(v.w, w, &e); p = b >> 9;
        if (p > p12) sgt += (double)e; else if (p == p12) atomicAdd(&hist[b & 0x1FFu], 1u);
    }
    #pragma unroll
    for (int off = 32; off > 0; off >>= 1) sgt += __shfl_down(sgt, off);
    if ((tid & 63) == 0) red[tid >> 6] = sgt;
    __syncthreads();
    if (tid == 0) {
        double S = 0.0;
        for (int i = 0; i < NT / 64; ++i) S += red[i];
        unsigned acc = c12in[g];
        double sab = 0.0;
        int b = 511;
        for (; b >= 0; --b) {
            unsigned h = hist[b];
            if (acc + h >= KSEL) break;     // k-th largest lives at this exact value
            acc += h;
            sab += (double)h * (double)__uint_as_float((p12 << 9) | (unsigned)b);
        }
        float tv = __uint_as_float((p12 << 9) | (unsigned)b);  // exact k-th largest
        // exact top-k sum with tie handling: (KSEL - acc) copies of tv are in the top-k
        topk_sum[g] = S + sab + (double)(KSEL - acc) * (double)tv;
    }
}

// ---------------- Final: channel deltas + stable top-3 indices ----------------
__global__ void final_kernel(const double* __restrict__ total_sum,
                             const double* __restrict__ topk_sum,
                             int* __restrict__ out) {
    __shared__ double delta[CCH];
    const int c = threadIdx.x;
    double th = 0.0, tot = 0.0;
    for (int b = 0; b < BN; ++b) {
        th  += topk_sum[b * CCH + c];
        tot += total_sum[b * CCH + c];
    }
    // delta_ref = 2*(mean_high - mean); ranking is monotone in (mean_high - mean)
    delta[c] = th / ((double)BN * (double)KSEL) - tot / ((double)BN * (double)HWSZ);
    __syncthreads();
    if (c == 0) {
        int chosen[3];
        for (int j = 0; j < 3; ++j) {
            double bv = -1e300; int bi = 0;
            for (int i = 0; i < CCH; ++i) {
                bool skip = false;
                for (int jj = 0; jj < j; ++jj) if (chosen[jj] == i) skip = true;
                if (!skip && delta[i] > bv) { bv = delta[i]; bi = i; }  // strict > : lower idx wins ties (stable argsort)
            }
            chosen[j] = bi;
            out[j] = bi;
        }
    }
}

extern "C" void kernel_launch(void* const* d_in, const int* in_sizes, int n_in,
                              void* d_out, int out_size, void* d_ws, size_t ws_size,
                              hipStream_t stream) {
    const float* hsi = (const float*)d_in[0];
    const float* w   = (const float*)d_in[1];
    int* out = (int*)d_out;

    char* ws = (char*)d_ws;
    double*   total_sum = (double*)(ws);              // 512*8 = 4 KB
    double*   topk_sum  = (double*)(ws + 4096);       // 4 KB
    unsigned* prefix1   = (unsigned*)(ws + 8192);     // 2 KB
    unsigned* c1v       = (unsigned*)(ws + 10240);    // 2 KB
    unsigned* prefix12  = (unsigned*)(ws + 12288);    // 2 KB
    unsigned* c12v      = (unsigned*)(ws + 14336);    // 2 KB

    hipLaunchKernelGGL(pass1_kernel, dim3(NG), dim3(NT), 0, stream, hsi, w, total_sum, prefix1, c1v);
    hipLaunchKernelGGL(pass2_kernel, dim3(NG), dim3(NT), 0, stream, hsi, w, prefix1, c1v, prefix12, c12v);
    hipLaunchKernelGGL(pass3_kernel, dim3(NG), dim3(NT), 0, stream, hsi, w, prefix12, c12v, topk_sum);
    hipLaunchKernelGGL(final_kernel, dim3(1), dim3(CCH), 0, stream, total_sum, topk_sum, out);
}

// Round 2
// 212.660 us; speedup vs baseline: 1.5372x; 1.5372x over previous
//
#include <hip/hip_runtime.h>

#define HWSZ 65536      // H*W
#define KSEL 32768u     // int(0.5*H*W)
#define CCH  128        // channels
#define BN   4          // batch
#define NG   (CCH * BN) // 512 groups; group g = b*CCH + c, contiguous HWSZ floats
#define NT   512        // threads per block (8 waves)

#define NBINS 8192              // uniform-in-e bins; width ~4.5e-5
#define BPC   (NBINS / NT)      // 16 bins per chunk (one chunk per thread)
#define NSUP  64                // superchunks (one wave finalizes)
#define CPS   (NT / NSUP)       // 8 chunks per superchunk

#define FIXSCALE 1073741824.0f           // 2^30 fixed-point for e
#define SUMMASK  ((1ull << 47) - 1ull)   // sum in bits[46:0], count in bits[63:47]

// ---------------- Pass A: single streaming pass ----------------
// Packed histogram: one ds_add_u64 per element. count<<47 | q(e).
// total = sum of all bin sums (exact in fixed point).
// topk  = bins above threshold + boundary bin partial at in-bin average.
__global__ void __launch_bounds__(NT) passA_kernel(
    const float* __restrict__ hsi, const float* __restrict__ wp,
    double* __restrict__ total_sum, double* __restrict__ topk_sum) {
    __shared__ unsigned long long hist[NBINS];      // 64 KB
    __shared__ unsigned long long chunkSum[NT];     // 4 KB
    __shared__ unsigned           chunkCnt[NT];     // 2 KB
    __shared__ unsigned long long superSum[NSUP];   // 512 B
    __shared__ unsigned           superCnt[NSUP];   // 256 B

    const int g   = blockIdx.x;
    const int tid = threadIdx.x;
    const float w = wp[0];

    // upper bound on e = -f1*ln(f1), f1 in (0, w): 1/e if w>=1/e else -w ln w
    float emax = (w < 0.367879441f) ? (-w * __logf(w)) : 0.3678794412f;
    emax *= 1.000004f;                     // fp slack so no value exceeds range
    const float binScale = (float)NBINS / emax;

    for (int i = tid; i < NBINS; i += NT) hist[i] = 0ull;
    __syncthreads();

    const float4* __restrict__ src = (const float4*)(hsi + (size_t)g * HWSZ);
    for (int i = 0; i < HWSZ / 4 / NT; ++i) {       // 32 coalesced float4 iters
        float4 v = src[(size_t)i * NT + tid];
        #pragma unroll
        for (int j = 0; j < 4; ++j) {
            float h  = (&v.x)[j];
            float f1 = h * w;
            float e  = -f1 * __logf(f1);            // e in (0, emax]
            unsigned ib = (unsigned)(e * binScale);
            ib = min(ib, (unsigned)(NBINS - 1));
            unsigned q = (unsigned)(e * FIXSCALE + 0.5f);   // e*2^30, fits u32
            atomicAdd(&hist[ib], (1ull << 47) | (unsigned long long)q);
        }
    }
    __syncthreads();

    // per-thread chunk aggregate (16 bins)
    {
        unsigned long long s = 0ull; unsigned c = 0u;
        const int base = tid * BPC;
        #pragma unroll
        for (int j = 0; j < BPC; ++j) {
            unsigned long long v = hist[base + j];
            s += (v & SUMMASK);
            c += (unsigned)(v >> 47);
        }
        chunkSum[tid] = s; chunkCnt[tid] = c;
    }
    __syncthreads();
    if (tid < NSUP) {
        unsigned long long s = 0ull; unsigned c = 0u;
        const int base = tid * CPS;
        #pragma unroll
        for (int j = 0; j < CPS; ++j) { s += chunkSum[base + j]; c += chunkCnt[base + j]; }
        superSum[tid] = s; superCnt[tid] = c;
    }
    __syncthreads();

    if (tid == 0) {
        // grand total (exact fixed-point sum of all entropies)
        unsigned long long tot = 0ull;
        for (int i = 0; i < NSUP; ++i) tot += superSum[i];
        total_sum[g] = (double)tot * (1.0 / (double)FIXSCALE);

        // locate k-th-largest threshold scanning from the top (high e = high bin)
        unsigned acc = 0u; unsigned long long accs = 0ull;
        int sc = NSUP - 1;
        for (; sc > 0; --sc) {
            unsigned c = superCnt[sc];
            if (acc + c >= KSEL) break;
            acc += c; accs += superSum[sc];
        }
        int ch = sc * CPS + (CPS - 1);
        for (; ch > sc * CPS; --ch) {
            unsigned c = chunkCnt[ch];
            if (acc + c >= KSEL) break;
            acc += c; accs += chunkSum[ch];
        }
        int b = ch * BPC + (BPC - 1);
        for (; b > ch * BPC; --b) {
            unsigned long long v = hist[b];
            unsigned c = (unsigned)(v >> 47);
            if (acc + c >= KSEL) break;
            acc += c; accs += (v & SUMMASK);
        }
        // boundary bin: take (KSEL-acc) items at the bin's average value.
        // error <= take * binwidth ~ 5e-4 abs on a ~1e4 sum -> 1.6e-8 on mean_high
        unsigned long long vb = hist[b];
        unsigned cb = (unsigned)(vb >> 47);
        unsigned long long sb = vb & SUMMASK;
        double take = (double)(KSEL - acc);
        double avg  = (cb > 0u) ? ((double)sb / (double)cb) : 0.0;
        topk_sum[g] = ((double)accs + take * avg) * (1.0 / (double)FIXSCALE);
    }
}

// ---------------- Final: channel deltas + stable top-3 indices ----------------
__global__ void final_kernel(const double* __restrict__ total_sum,
                             const double* __restrict__ topk_sum,
                             int* __restrict__ out) {
    __shared__ double delta[CCH];
    const int c = threadIdx.x;
    double th = 0.0, tot = 0.0;
    for (int b = 0; b < BN; ++b) {
        th  += topk_sum[b * CCH + c];
        tot += total_sum[b * CCH + c];
    }
    // ranking monotone in (mean_high - mean)
    delta[c] = th / ((double)BN * (double)KSEL) - tot / ((double)BN * (double)HWSZ);
    __syncthreads();
    if (c == 0) {
        int chosen[3];
        for (int j = 0; j < 3; ++j) {
            double bv = -1e300; int bi = 0;
            for (int i = 0; i < CCH; ++i) {
                bool skip = false;
                for (int jj = 0; jj < j; ++jj) if (chosen[jj] == i) skip = true;
                if (!skip && delta[i] > bv) { bv = delta[i]; bi = i; }  // strict >: lower idx wins ties
            }
            chosen[j] = bi;
            out[j] = bi;
        }
    }
}

extern "C" void kernel_launch(void* const* d_in, const int* in_sizes, int n_in,
                              void* d_out, int out_size, void* d_ws, size_t ws_size,
                              hipStream_t stream) {
    const float* hsi = (const float*)d_in[0];
    const float* w   = (const float*)d_in[1];
    int* out = (int*)d_out;

    char* ws = (char*)d_ws;
    double* total_sum = (double*)(ws);          // 512*8 = 4 KB
    double* topk_sum  = (double*)(ws + 4096);   // 4 KB

    hipLaunchKernelGGL(passA_kernel, dim3(NG), dim3(NT), 0, stream, hsi, w, total_sum, topk_sum);
    hipLaunchKernelGGL(final_kernel, dim3(1), dim3(CCH), 0, stream, total_sum, topk_sum, out);
}